// Round 1
// baseline (3156.199 us; speedup 1.0000x reference)
//
#include <hip/hip_runtime.h>
#include <math.h>

#define TT 256
#define HH 100
#define GG 400
#define BB 512

// LDS float offsets
#define OFF_H   40000          // h[2][100]
#define OFF_XG  40200          // union: xin[2][100] | gates[2][300]
#define LDS_FLOATS 40800       // 163,200 bytes

__device__ __forceinline__ float sigm(float v) {
    return 1.0f / (1.0f + expf(-v));
}

extern "C" __global__ void __launch_bounds__(512, 1)
lstm_fused(const float* __restrict__ x,          // [B][T][2]
           const float* __restrict__ W_ih0,      // [400][2]
           const float* __restrict__ W_ih_rest,  // [2][400][100]
           const float* __restrict__ W_hh,       // [3][400][100]
           const float* __restrict__ b_ih,       // [3][400]
           const float* __restrict__ b_hh,       // [3][400]
           const float* __restrict__ head_w,     // [100]
           const float* __restrict__ head_b,     // [1]
           float* __restrict__ out,              // [B]
           float* __restrict__ hs)               // ws: [B][T][100]
{
    extern __shared__ float lds[];
    float* whh_s = lds;            // [400][100] row-major
    float* h_s   = lds + OFF_H;    // [2][100]
    float* xg_s  = lds + OFF_XG;   // xin [2][100] / gates [2][300]

    const int tid = threadIdx.x;
    const int b0  = blockIdx.x * 2;
    const int g   = tid;           // gate id when tid < 400

    float wih[100];                // per-gate W_ih row (layers 1,2), kept in VGPRs
    float w0a = 0.f, w0b = 0.f;    // layer-0 W_ih row (D_IN = 2)
    float bias = 0.f;
    float c0 = 0.f, c1 = 0.f;      // cell state, owned by threads tid<100 (unit j)

    for (int l = 0; l < 3; ++l) {
        // ---- stage W_hh[l] into LDS ----
        {
            const float4* src = (const float4*)(W_hh + (size_t)l * 40000);
            float4* dst = (float4*)whh_s;
            for (int i = tid; i < 10000; i += 512) dst[i] = src[i];
        }
        // ---- per-gate weights into registers ----
        if (g < GG) {
            bias = b_ih[l * GG + g] + b_hh[l * GG + g];
            if (l == 0) {
                float2 w = *(const float2*)(W_ih0 + g * 2);
                w0a = w.x; w0b = w.y;
            } else {
                const float4* src = (const float4*)(W_ih_rest + (size_t)(l - 1) * 40000 + g * 100);
                #pragma unroll
                for (int q = 0; q < 25; ++q) {
                    float4 v = src[q];
                    wih[4*q+0] = v.x; wih[4*q+1] = v.y;
                    wih[4*q+2] = v.z; wih[4*q+3] = v.w;
                }
            }
        }
        // ---- reset state ----
        if (tid < 2 * HH) h_s[tid] = 0.f;
        c0 = 0.f; c1 = 0.f;
        __syncthreads();

        for (int t = 0; t < TT; ++t) {
            // phase0: stage x_in from hs (layers >= 1); 50 threads, float4
            if (l > 0 && tid < 50) {
                int r = tid / 25, q = tid - r * 25;
                ((float4*)(xg_s + r * HH))[q] =
                    ((const float4*)(hs + ((size_t)(b0 + r) * TT + t) * HH))[q];
            }
            __syncthreads();   // A: x_in visible (and prior gate reads done)

            // phase1: gate pre-activations
            float a0 = bias, a1 = bias;
            if (g < GG) {
                const float4* wr = (const float4*)(whh_s) + g * 25;
                const float4* h0 = (const float4*)(h_s);
                const float4* h1 = (const float4*)(h_s + HH);
                if (l == 0) {
                    float2 xa = *(const float2*)(x + ((size_t)(b0 + 0) * TT + t) * 2);
                    float2 xb = *(const float2*)(x + ((size_t)(b0 + 1) * TT + t) * 2);
                    a0 += w0a * xa.x + w0b * xa.y;
                    a1 += w0a * xb.x + w0b * xb.y;
                    #pragma unroll
                    for (int q = 0; q < 25; ++q) {
                        float4 w = wr[q], ha = h0[q], hb = h1[q];
                        a0 += w.x*ha.x + w.y*ha.y + w.z*ha.z + w.w*ha.w;
                        a1 += w.x*hb.x + w.y*hb.y + w.z*hb.z + w.w*hb.w;
                    }
                } else {
                    const float4* x0 = (const float4*)(xg_s);
                    const float4* x1 = (const float4*)(xg_s + HH);
                    #pragma unroll
                    for (int q = 0; q < 25; ++q) {
                        float4 w = wr[q], ha = h0[q], hb = h1[q];
                        float4 xa = x0[q], xb = x1[q];
                        a0 += w.x*ha.x + w.y*ha.y + w.z*ha.z + w.w*ha.w;
                        a1 += w.x*hb.x + w.y*hb.y + w.z*hb.z + w.w*hb.w;
                        a0 += wih[4*q+0]*xa.x + wih[4*q+1]*xa.y + wih[4*q+2]*xa.z + wih[4*q+3]*xa.w;
                        a1 += wih[4*q+0]*xb.x + wih[4*q+1]*xb.y + wih[4*q+2]*xb.z + wih[4*q+3]*xb.w;
                    }
                }
            }
            __syncthreads();   // B: all h/x/W reads done -> may overwrite xg

            // phase2a: publish f,g,o gate pre-activations
            if (g >= HH && g < GG) {
                xg_s[0 * 300 + (g - HH)] = a0;
                xg_s[1 * 300 + (g - HH)] = a1;
            }
            __syncthreads();   // C

            // phase2b: per-unit activations + state update (threads 0..99, both rows)
            if (tid < HH) {
                const int j = tid;
                {
                    float f_ = xg_s[0*300 + j];
                    float g_ = xg_s[0*300 + 100 + j];
                    float o_ = xg_s[0*300 + 200 + j];
                    float cc = sigm(f_) * c0 + sigm(a0) * tanhf(g_);
                    c0 = cc;
                    float hh2 = sigm(o_) * tanhf(cc);
                    h_s[j] = hh2;
                    if (l < 2) hs[((size_t)(b0 + 0) * TT + t) * HH + j] = hh2;
                }
                {
                    float f_ = xg_s[1*300 + j];
                    float g_ = xg_s[1*300 + 100 + j];
                    float o_ = xg_s[1*300 + 200 + j];
                    float cc = sigm(f_) * c1 + sigm(a1) * tanhf(g_);
                    c1 = cc;
                    float hh2 = sigm(o_) * tanhf(cc);
                    h_s[HH + j] = hh2;
                    if (l < 2) hs[((size_t)(b0 + 1) * TT + t) * HH + j] = hh2;
                }
            }
            __syncthreads();   // D: h ready for next step; gates consumed
        }
    }

    // head: out[b] = dot(h_last, head_w) + head_b
    const int lane = tid & 63, wv = tid >> 6;
    if (wv < 2) {
        float p = 0.f;
        for (int k = lane; k < HH; k += 64) p += h_s[wv * HH + k] * head_w[k];
        #pragma unroll
        for (int off = 32; off; off >>= 1) p += __shfl_down(p, off);
        if (lane == 0) out[b0 + wv] = p + head_b[0];
    }
}

extern "C" void kernel_launch(void* const* d_in, const int* in_sizes, int n_in,
                              void* d_out, int out_size, void* d_ws, size_t ws_size,
                              hipStream_t stream) {
    const float* x         = (const float*)d_in[0];
    const float* W_ih0     = (const float*)d_in[1];
    const float* W_ih_rest = (const float*)d_in[2];
    const float* W_hh      = (const float*)d_in[3];
    const float* b_ih      = (const float*)d_in[4];
    const float* b_hh      = (const float*)d_in[5];
    const float* head_w    = (const float*)d_in[6];
    const float* head_b    = (const float*)d_in[7];
    float* out = (float*)d_out;
    float* hs  = (float*)d_ws;   // [512][256][100] fp32 = 52.4 MB

    const int lds_bytes = LDS_FLOATS * 4;   // 163,200 B
    hipFuncSetAttribute((const void*)lstm_fused,
                        hipFuncAttributeMaxDynamicSharedMemorySize, lds_bytes);

    lstm_fused<<<256, 512, lds_bytes, stream>>>(
        x, W_ih0, W_ih_rest, W_hh, b_ih, b_hh, head_w, head_b, out, hs);
}

// Round 2
// 2295.581 us; speedup vs baseline: 1.3749x; 1.3749x over previous
//
#include <hip/hip_runtime.h>
#include <math.h>

#define TT 256
#define HH 100
#define GG 400
#define BB 512

// ---------------- raw barrier: LDS-drain only, keep global loads in flight ----
__device__ __forceinline__ void bar_lds() {
    asm volatile("s_waitcnt lgkmcnt(0)" ::: "memory");
    __builtin_amdgcn_s_barrier();
    asm volatile("" ::: "memory");
}

// ============================ recurrence kernel ==============================
// LK: 0 = first layer (x input, writes hs), 1 = middle (pre input, writes hs),
//     2 = last (pre input, writes head output only)
template<int LK>
__global__ void __launch_bounds__(512, 2)
lstm_recur(const float* __restrict__ x,        // [B][T][2]      (LK==0)
           const float* __restrict__ pre,      // [T][B][400]    (LK>=1, bias folded)
           const float* __restrict__ Whh,      // [400][100] this layer
           const float* __restrict__ Wih0,     // [400][2]       (LK==0)
           const float* __restrict__ bih,      // [400]          (LK==0)
           const float* __restrict__ bhh,      // [400]          (LK==0)
           const float* __restrict__ head_w,   // [100]
           const float* __restrict__ head_b,   // [1]
           float* __restrict__ hs,             // [B][T][100]    (LK<2 out)
           float* __restrict__ out)            // [B]            (LK==2 out)
{
    __shared__ float h_s[2 * HH];     // h for rows b0, b0+1
    __shared__ float gbuf[2 * GG];    // activated gates, rows 0/1

    const int tid = threadIdx.x;
    const int b0  = blockIdx.x * 2;

    float whh[HH];
    float w0a = 0.f, w0b = 0.f, bias = 0.f;
    if (tid < GG) {
        const float4* wsrc = (const float4*)(Whh + tid * HH);
        #pragma unroll
        for (int q = 0; q < 25; ++q) {
            float4 v = wsrc[q];
            whh[4*q+0] = v.x; whh[4*q+1] = v.y; whh[4*q+2] = v.z; whh[4*q+3] = v.w;
        }
        if (LK == 0) {
            float2 w = *(const float2*)(Wih0 + tid * 2);
            w0a = w.x; w0b = w.y;
            bias = bih[tid] + bhh[tid];
        }
    }
    if (tid < 2 * HH) h_s[tid] = 0.f;
    float c = 0.f;                    // cell state for (row = tid/100, j = tid%100), tid<200
    __syncthreads();

    // prefetch t = 0 inputs
    float p0 = 0.f, p1 = 0.f;
    float2 xa = {0.f, 0.f}, xb = {0.f, 0.f};
    if (tid < GG) {
        if (LK == 0) {
            xa = *(const float2*)(x + (size_t)(b0    ) * TT * 2);
            xb = *(const float2*)(x + (size_t)(b0 + 1) * TT * 2);
        } else {
            p0 = pre[((size_t)0 * BB + b0    ) * GG + tid];
            p1 = pre[((size_t)0 * BB + b0 + 1) * GG + tid];
        }
    }

    for (int t = 0; t < TT; ++t) {
        if (tid < GG) {
            float a0e, a0o, a1e, a1o;
            if (LK == 0) {
                a0e = bias + w0a * xa.x;  a0o = w0b * xa.y;
                a1e = bias + w0a * xb.x;  a1o = w0b * xb.y;
            } else {
                a0e = p0; a0o = 0.f;
                a1e = p1; a1o = 0.f;
            }
            // software-pipelined prefetch for t+1 (stays in flight across raw barriers)
            const int tn = (t + 1 < TT) ? t + 1 : t;
            if (LK == 0) {
                xa = *(const float2*)(x + ((size_t)(b0    ) * TT + tn) * 2);
                xb = *(const float2*)(x + ((size_t)(b0 + 1) * TT + tn) * 2);
            } else {
                p0 = pre[((size_t)tn * BB + b0    ) * GG + tid];
                p1 = pre[((size_t)tn * BB + b0 + 1) * GG + tid];
            }

            const float4* h0 = (const float4*)(h_s);
            const float4* h1 = (const float4*)(h_s + HH);
            #pragma unroll
            for (int q = 0; q < 25; ++q) {
                float4 ha = h0[q], hb = h1[q];
                a0e += whh[4*q+0] * ha.x; a0o += whh[4*q+1] * ha.y;
                a0e += whh[4*q+2] * ha.z; a0o += whh[4*q+3] * ha.w;
                a1e += whh[4*q+0] * hb.x; a1o += whh[4*q+1] * hb.y;
                a1e += whh[4*q+2] * hb.z; a1o += whh[4*q+3] * hb.w;
            }
            float a0 = a0e + a0o, a1 = a1e + a1o;

            // branch-free activation: gates 200..299 are tanh = 2*sigm(2a)-1
            const bool isG = (tid >= 200 && tid < 300);
            float v0 = isG ? 2.f * a0 : a0;
            float v1 = isG ? 2.f * a1 : a1;
            float s0 = 1.f / (1.f + __expf(-v0));
            float s1 = 1.f / (1.f + __expf(-v1));
            if (isG) { s0 = 2.f * s0 - 1.f; s1 = 2.f * s1 - 1.f; }
            gbuf[tid]      = s0;
            gbuf[GG + tid] = s1;
        }
        bar_lds();   // gates visible; all h_s/x readers done

        if (tid < 2 * HH) {
            const int r = (tid >= HH) ? 1 : 0;
            const int j = tid - r * HH;
            const float* gb = gbuf + r * GG;
            float I = gb[j], F = gb[HH + j], G = gb[2*HH + j], O = gb[3*HH + j];
            c = F * c + I * G;
            float th = 2.f / (1.f + __expf(-2.f * c)) - 1.f;
            float hv = O * th;
            h_s[tid] = hv;
            if (LK < 2) hs[((size_t)(b0 + r) * TT + t) * HH + j] = hv;
        }
        bar_lds();   // h ready for next step; gbuf consumed
    }

    if (LK == 2) {
        const int lane = tid & 63, wv = tid >> 6;
        if (wv < 2) {
            float p = 0.f;
            for (int k = lane; k < HH; k += 64) p += h_s[wv * HH + k] * head_w[k];
            #pragma unroll
            for (int off = 32; off; off >>= 1) p += __shfl_down(p, off);
            if (lane == 0) out[b0 + wv] = p + head_b[0];
        }
    }
}

// ============================ x-projection GEMM ==============================
// pre[row][g] = b_ih[g]+b_hh[g] + sum_j hs[b][t][j] * Wih[g][j],  row = t*512+b
__global__ void __launch_bounds__(512, 2)
gemm_pre(const float* __restrict__ hs,     // [B][T][100]
         const float* __restrict__ Wih,    // [400][100]
         const float* __restrict__ bih,    // [400]
         const float* __restrict__ bhh,    // [400]
         float* __restrict__ pre)          // [T][B][400]
{
    const int g = threadIdx.x;
    if (g >= GG) return;                   // no barriers below -> safe early exit

    float wih[HH];
    const float4* wsrc = (const float4*)(Wih + g * HH);
    #pragma unroll
    for (int q = 0; q < 25; ++q) {
        float4 v = wsrc[q];
        wih[4*q+0] = v.x; wih[4*q+1] = v.y; wih[4*q+2] = v.z; wih[4*q+3] = v.w;
    }
    const float bs = bih[g] + bhh[g];

    const int row0 = blockIdx.x * 128;
    for (int r = 0; r < 128; ++r) {
        const int row = row0 + r;          // row = t*512 + b
        const int t = row >> 9, b = row & 511;
        const float4* ap = (const float4*)(hs + ((size_t)b * TT + t) * HH);
        float ae = bs, ao = 0.f;
        #pragma unroll
        for (int q = 0; q < 25; ++q) {
            float4 av = ap[q];
            ae += wih[4*q+0] * av.x; ao += wih[4*q+1] * av.y;
            ae += wih[4*q+2] * av.z; ao += wih[4*q+3] * av.w;
        }
        pre[(size_t)row * GG + g] = ae + ao;
    }
}

// ===================== fallback (R1 kernel) if ws too small ==================
#define OFF_H   40000
#define OFF_XG  40200
#define LDS_FLOATS 40800

__device__ __forceinline__ float sigm_(float v) { return 1.0f / (1.0f + expf(-v)); }

extern "C" __global__ void __launch_bounds__(512, 1)
lstm_fused(const float* __restrict__ x, const float* __restrict__ W_ih0,
           const float* __restrict__ W_ih_rest, const float* __restrict__ W_hh,
           const float* __restrict__ b_ih, const float* __restrict__ b_hh,
           const float* __restrict__ head_w, const float* __restrict__ head_b,
           float* __restrict__ out, float* __restrict__ hs)
{
    extern __shared__ float lds[];
    float* whh_s = lds;
    float* h_s   = lds + OFF_H;
    float* xg_s  = lds + OFF_XG;
    const int tid = threadIdx.x;
    const int b0  = blockIdx.x * 2;
    const int g   = tid;
    float wih[100]; float w0a = 0.f, w0b = 0.f, bias = 0.f, c0 = 0.f, c1 = 0.f;
    for (int l = 0; l < 3; ++l) {
        { const float4* src = (const float4*)(W_hh + (size_t)l * 40000);
          float4* dst = (float4*)whh_s;
          for (int i = tid; i < 10000; i += 512) dst[i] = src[i]; }
        if (g < GG) {
            bias = b_ih[l * GG + g] + b_hh[l * GG + g];
            if (l == 0) { float2 w = *(const float2*)(W_ih0 + g * 2); w0a = w.x; w0b = w.y; }
            else {
                const float4* src = (const float4*)(W_ih_rest + (size_t)(l - 1) * 40000 + g * 100);
                #pragma unroll
                for (int q = 0; q < 25; ++q) { float4 v = src[q];
                    wih[4*q]=v.x; wih[4*q+1]=v.y; wih[4*q+2]=v.z; wih[4*q+3]=v.w; }
            }
        }
        if (tid < 2 * HH) h_s[tid] = 0.f;
        c0 = 0.f; c1 = 0.f;
        __syncthreads();
        for (int t = 0; t < TT; ++t) {
            if (l > 0 && tid < 50) {
                int r = tid / 25, q = tid - r * 25;
                ((float4*)(xg_s + r * HH))[q] =
                    ((const float4*)(hs + ((size_t)(b0 + r) * TT + t) * HH))[q];
            }
            __syncthreads();
            float a0 = bias, a1 = bias;
            if (g < GG) {
                const float4* wr = (const float4*)(whh_s) + g * 25;
                const float4* h0 = (const float4*)(h_s);
                const float4* h1 = (const float4*)(h_s + HH);
                if (l == 0) {
                    float2 xa = *(const float2*)(x + ((size_t)(b0) * TT + t) * 2);
                    float2 xb = *(const float2*)(x + ((size_t)(b0 + 1) * TT + t) * 2);
                    a0 += w0a * xa.x + w0b * xa.y; a1 += w0a * xb.x + w0b * xb.y;
                    #pragma unroll
                    for (int q = 0; q < 25; ++q) { float4 w = wr[q], ha = h0[q], hb = h1[q];
                        a0 += w.x*ha.x + w.y*ha.y + w.z*ha.z + w.w*ha.w;
                        a1 += w.x*hb.x + w.y*hb.y + w.z*hb.z + w.w*hb.w; }
                } else {
                    const float4* x0 = (const float4*)(xg_s);
                    const float4* x1 = (const float4*)(xg_s + HH);
                    #pragma unroll
                    for (int q = 0; q < 25; ++q) { float4 w = wr[q], ha = h0[q], hb = h1[q];
                        float4 xv = x0[q], xw = x1[q];
                        a0 += w.x*ha.x + w.y*ha.y + w.z*ha.z + w.w*ha.w;
                        a1 += w.x*hb.x + w.y*hb.y + w.z*hb.z + w.w*hb.w;
                        a0 += wih[4*q]*xv.x + wih[4*q+1]*xv.y + wih[4*q+2]*xv.z + wih[4*q+3]*xv.w;
                        a1 += wih[4*q]*xw.x + wih[4*q+1]*xw.y + wih[4*q+2]*xw.z + wih[4*q+3]*xw.w; }
                }
            }
            __syncthreads();
            if (g >= HH && g < GG) { xg_s[(g - HH)] = a0; xg_s[300 + (g - HH)] = a1; }
            __syncthreads();
            if (tid < HH) {
                const int j = tid;
                { float f_ = xg_s[j], g_ = xg_s[100 + j], o_ = xg_s[200 + j];
                  float cc = sigm_(f_) * c0 + sigm_(a0) * tanhf(g_); c0 = cc;
                  float hh2 = sigm_(o_) * tanhf(cc); h_s[j] = hh2;
                  if (l < 2) hs[((size_t)(b0) * TT + t) * HH + j] = hh2; }
                { float f_ = xg_s[300 + j], g_ = xg_s[400 + j], o_ = xg_s[500 + j];
                  float cc = sigm_(f_) * c1 + sigm_(a1) * tanhf(g_); c1 = cc;
                  float hh2 = sigm_(o_) * tanhf(cc); h_s[HH + j] = hh2;
                  if (l < 2) hs[((size_t)(b0 + 1) * TT + t) * HH + j] = hh2; }
            }
            __syncthreads();
        }
    }
    const int lane = tid & 63, wv = tid >> 6;
    if (wv < 2) {
        float p = 0.f;
        for (int k = lane; k < HH; k += 64) p += h_s[wv * HH + k] * head_w[k];
        #pragma unroll
        for (int off = 32; off; off >>= 1) p += __shfl_down(p, off);
        if (lane == 0) out[b0 + wv] = p + head_b[0];
    }
}

// =============================================================================
extern "C" void kernel_launch(void* const* d_in, const int* in_sizes, int n_in,
                              void* d_out, int out_size, void* d_ws, size_t ws_size,
                              hipStream_t stream) {
    const float* x         = (const float*)d_in[0];
    const float* W_ih0     = (const float*)d_in[1];
    const float* W_ih_rest = (const float*)d_in[2];
    const float* W_hh      = (const float*)d_in[3];
    const float* b_ih      = (const float*)d_in[4];
    const float* b_hh      = (const float*)d_in[5];
    const float* head_w    = (const float*)d_in[6];
    const float* head_b    = (const float*)d_in[7];
    float* out = (float*)d_out;

    const size_t HS_BYTES  = (size_t)BB * TT * HH * 4;   // 52,428,800
    const size_t PRE_BYTES = (size_t)TT * BB * GG * 4;   // 209,715,200

    if (ws_size >= HS_BYTES + PRE_BYTES) {
        float* hs  = (float*)d_ws;
        float* pre = (float*)((char*)d_ws + HS_BYTES);

        lstm_recur<0><<<256, 512, 0, stream>>>(
            x, nullptr, W_hh, W_ih0, b_ih, b_hh, head_w, head_b, hs, out);

        gemm_pre<<<1024, 512, 0, stream>>>(hs, W_ih_rest, b_ih + GG, b_hh + GG, pre);
        lstm_recur<1><<<256, 512, 0, stream>>>(
            nullptr, pre, W_hh + 40000, nullptr, nullptr, nullptr, head_w, head_b, hs, out);

        gemm_pre<<<1024, 512, 0, stream>>>(hs, W_ih_rest + 40000, b_ih + 2*GG, b_hh + 2*GG, pre);
        lstm_recur<2><<<256, 512, 0, stream>>>(
            nullptr, pre, W_hh + 80000, nullptr, nullptr, nullptr, head_w, head_b, hs, out);
    } else {
        float* hs = (float*)d_ws;
        const int lds_bytes = LDS_FLOATS * 4;
        hipFuncSetAttribute((const void*)lstm_fused,
                            hipFuncAttributeMaxDynamicSharedMemorySize, lds_bytes);
        lstm_fused<<<256, 512, lds_bytes, stream>>>(
            x, W_ih0, W_ih_rest, W_hh, b_ih, b_hh, head_w, head_b, out, hs);
    }
}

// Round 3
// 1492.993 us; speedup vs baseline: 2.1140x; 1.5376x over previous
//
#include <hip/hip_runtime.h>
#include <math.h>

#define TT 256
#define HH 100
#define GG 400
#define BB 512

// LDS-drain-only barrier: keeps global loads/stores in flight
__device__ __forceinline__ void bar_lds() {
    asm volatile("s_waitcnt lgkmcnt(0)" ::: "memory");
    __builtin_amdgcn_s_barrier();
    asm volatile("" ::: "memory");
}

// ============================ recurrence kernel ==============================
// 256 blocks x 512 threads, 2 batch rows per block, ONE barrier per step.
// Thread map (tid<400): unit u = tid>>2, gate type ty = tid&3 (0=i,1=f,2=g,3=o),
// gate row g = ty*100+u. i/f/g/o of unit u live in 4 adjacent lanes -> shuffle
// combine. h double-buffered in LDS: step t reads hbuf[t&1], writes hbuf[t&1^1].
template<int LK>
__global__ void __launch_bounds__(512, 2)
lstm_recur(const float* __restrict__ x,        // [B][T][2]   (LK==0)
           const float* __restrict__ pre,      // [T*B][400]  (LK>=1, bias folded)
           const float* __restrict__ Whh,      // [400][100]
           const float* __restrict__ Wih0,     // [400][2]    (LK==0)
           const float* __restrict__ bih,      // [400]       (LK==0)
           const float* __restrict__ bhh,      // [400]       (LK==0)
           const float* __restrict__ head_w,   // [100]
           const float* __restrict__ head_b,   // [1]
           float* __restrict__ hs,             // [B][T][100] (LK<2 out)
           float* __restrict__ out)            // [B]         (LK==2 out)
{
    __shared__ float hbuf[2][2][HH];   // [buf][row][unit]

    const int tid = threadIdx.x;
    const int b0  = blockIdx.x * 2;
    const int u   = tid >> 2, ty = tid & 3;
    const int g   = ty * HH + u;
    const bool on = (tid < GG);

    float whh[HH];
    float w0a = 0.f, w0b = 0.f, bias = 0.f;
    if (on) {
        const float4* ws = (const float4*)(Whh + g * HH);
        #pragma unroll
        for (int q = 0; q < 25; ++q) {
            float4 v = ws[q];
            whh[4*q+0] = v.x; whh[4*q+1] = v.y; whh[4*q+2] = v.z; whh[4*q+3] = v.w;
        }
        if (LK == 0) {
            w0a = Wih0[2*g]; w0b = Wih0[2*g+1];
            bias = bih[g] + bhh[g];
        }
    }
    if (tid < 400) ((float*)hbuf)[tid] = 0.f;   // zero both buffers (2*2*100)
    float c0 = 0.f, c1 = 0.f;                   // owned by ty==0 lanes
    __syncthreads();

    // prefetch t=0 inputs
    float p0 = 0.f, p1 = 0.f;
    float2 xa = {0.f, 0.f}, xb = {0.f, 0.f};
    if (on) {
        if (LK == 0) {
            xa = *(const float2*)(x + (size_t)(b0    ) * TT * 2);
            xb = *(const float2*)(x + (size_t)(b0 + 1) * TT * 2);
        } else {
            p0 = pre[((size_t)0 * BB + b0    ) * GG + g];
            p1 = pre[((size_t)0 * BB + b0 + 1) * GG + g];
        }
    }

    for (int t = 0; t < TT; ++t) {
        const int cur = t & 1, nxt = cur ^ 1;
        if (on) {
            float a0e, a0o, a1e, a1o;
            if (LK == 0) {
                a0e = bias + w0a * xa.x;  a0o = w0b * xa.y;
                a1e = bias + w0a * xb.x;  a1o = w0b * xb.y;
            } else {
                a0e = p0; a0o = 0.f;
                a1e = p1; a1o = 0.f;
            }
            // prefetch t+1 (stays in flight across the barrier)
            const int tn = (t + 1 < TT) ? t + 1 : t;
            if (LK == 0) {
                xa = *(const float2*)(x + ((size_t)(b0    ) * TT + tn) * 2);
                xb = *(const float2*)(x + ((size_t)(b0 + 1) * TT + tn) * 2);
            } else {
                p0 = pre[((size_t)tn * BB + b0    ) * GG + g];
                p1 = pre[((size_t)tn * BB + b0 + 1) * GG + g];
            }

            const float4* h0 = (const float4*)(hbuf[cur][0]);
            const float4* h1 = (const float4*)(hbuf[cur][1]);
            #pragma unroll
            for (int q = 0; q < 25; ++q) {
                float4 ha = h0[q], hb = h1[q];
                a0e += whh[4*q+0] * ha.x; a0o += whh[4*q+1] * ha.y;
                a0e += whh[4*q+2] * ha.z; a0o += whh[4*q+3] * ha.w;
                a1e += whh[4*q+0] * hb.x; a1o += whh[4*q+1] * hb.y;
                a1e += whh[4*q+2] * hb.z; a1o += whh[4*q+3] * hb.w;
            }
            float a0 = a0e + a0o, a1 = a1e + a1o;

            // activation: ty==2 is tanh = 2*sigm(2a)-1, others sigmoid
            const bool isG = (ty == 2);
            float v0 = isG ? 2.f * a0 : a0;
            float v1 = isG ? 2.f * a1 : a1;
            float s0 = 1.f / (1.f + __expf(-v0));
            float s1 = 1.f / (1.f + __expf(-v1));
            if (isG) { s0 = 2.f * s0 - 1.f; s1 = 2.f * s1 - 1.f; }

            // 4-lane group combine: lanes [i,f,g,o]
            float B0 = __shfl_xor(s0, 1), B1 = __shfl_xor(s1, 1); // ty0: sig(f)
            float C0 = __shfl_xor(s0, 2), C1 = __shfl_xor(s1, 2); // ty0: tanh(g)
            float D0 = __shfl_xor(B0, 2), D1 = __shfl_xor(B1, 2); // ty0: sig(o)

            if (ty == 0) {
                c0 = B0 * c0 + s0 * C0;
                float th0 = 2.f / (1.f + __expf(-2.f * c0)) - 1.f;
                float hv0 = D0 * th0;
                hbuf[nxt][0][u] = hv0;
                c1 = B1 * c1 + s1 * C1;
                float th1 = 2.f / (1.f + __expf(-2.f * c1)) - 1.f;
                float hv1 = D1 * th1;
                hbuf[nxt][1][u] = hv1;
                if (LK < 2) {
                    hs[((size_t)(b0    ) * TT + t) * HH + u] = hv0;
                    hs[((size_t)(b0 + 1) * TT + t) * HH + u] = hv1;
                }
            }
        }
        bar_lds();   // h(t) visible; also orders reuse of hbuf[cur] next step
    }

    // head: final h is in hbuf[0] (t=255 wrote nxt=0)
    const int lane = tid & 63, wv = tid >> 6;
    if (wv < 2) {
        float p = 0.f;
        if (LK == 2) {
            p = hbuf[0][wv][lane] * head_w[lane];
            if (lane < 36) p += hbuf[0][wv][64 + lane] * head_w[64 + lane];
            #pragma unroll
            for (int off = 32; off; off >>= 1) p += __shfl_down(p, off);
            if (lane == 0) out[b0 + wv] = p + head_b[0];
        }
    }
}

// ============================ x-projection GEMM ==============================
// pre[row][g] = bias[g] + sum_k hs[b][t][k]*Wih[g][k], row = t*512+b.
// M=131072, N=400, K=100. Tiled: block(320) = 64 rows x 80 gates, frag 4x4.
// LDS k-major with XOR swizzle on A rows (transpose-stage conflict fix).
__global__ void __launch_bounds__(320, 2)
gemm_pre(const float* __restrict__ hs,     // [B][T][100]
         const float* __restrict__ Wih,    // [400][100]
         const float* __restrict__ bih,    // [400]
         const float* __restrict__ bhh,    // [400]
         float* __restrict__ pre)          // [M][400]
{
    __shared__ float A_s[100 * 64];        // k-major, swizzled
    __shared__ float W_s[100 * 80];        // k-major

    const int tid = threadIdx.x;
    const int ti  = tid / 20;              // 0..15 row group
    const int tj  = tid % 20;              // 0..19 gate group
    const int row0   = blockIdx.x * 64;    // 64 rows, same t (512%64==0)
    const int t      = row0 >> 9;
    const int b_base = row0 & 511;
    const int gbase  = blockIdx.y * 80;

    // ---- stage A: 1600 float4, 5 per thread; kq-inner for coalescing ----
    #pragma unroll
    for (int s = 0; s < 5; ++s) {
        const int L  = tid + 320 * s;
        const int r  = L / 25, kq = L % 25;
        float4 v = *(const float4*)(hs + ((size_t)(b_base + r) * TT + t) * HH + 4 * kq);
        const int r4 = r >> 2, rm = r & 3;
        // A_addr(k,r) = k*64 + ((r>>2 ^ (k>>2 & 15))<<2) + (r&3)
        A_s[(4*kq+0)*64 + (((r4) ^ (kq & 15)) << 2) + rm] = v.x;
        A_s[(4*kq+1)*64 + (((r4) ^ (kq & 15)) << 2) + rm] = v.y;
        A_s[(4*kq+2)*64 + (((r4) ^ (kq & 15)) << 2) + rm] = v.z;
        A_s[(4*kq+3)*64 + (((r4) ^ (kq & 15)) << 2) + rm] = v.w;
    }
    // ---- stage W: 2000 float4; gl-inner writes conflict-free ----
    for (int L = tid; L < 2000; L += 320) {
        const int kq = L / 80, gl = L % 80;
        float4 v = *(const float4*)(Wih + (size_t)(gbase + gl) * HH + 4 * kq);
        W_s[(4*kq+0)*80 + gl] = v.x;
        W_s[(4*kq+1)*80 + gl] = v.y;
        W_s[(4*kq+2)*80 + gl] = v.z;
        W_s[(4*kq+3)*80 + gl] = v.w;
    }
    __syncthreads();

    // ---- init acc with bias ----
    float4 bs;
    {
        const float4 b1 = *(const float4*)(bih + gbase + 4 * tj);
        const float4 b2 = *(const float4*)(bhh + gbase + 4 * tj);
        bs.x = b1.x + b2.x; bs.y = b1.y + b2.y; bs.z = b1.z + b2.z; bs.w = b1.w + b2.w;
    }
    float acc[4][4];
    #pragma unroll
    for (int r = 0; r < 4; ++r) {
        acc[r][0] = bs.x; acc[r][1] = bs.y; acc[r][2] = bs.z; acc[r][3] = bs.w;
    }

    // ---- main loop: k in groups of 4 ----
    #pragma unroll 5
    for (int k4 = 0; k4 < 25; ++k4) {
        const int axo = ((ti ^ (k4 & 15)) << 2);
        float4 a[4], w[4];
        #pragma unroll
        for (int e = 0; e < 4; ++e) {
            a[e] = *(const float4*)&A_s[(4*k4+e)*64 + axo];
            w[e] = *(const float4*)&W_s[(4*k4+e)*80 + (tj << 2)];
        }
        #pragma unroll
        for (int e = 0; e < 4; ++e) {
            acc[0][0] += a[e].x * w[e].x; acc[0][1] += a[e].x * w[e].y;
            acc[0][2] += a[e].x * w[e].z; acc[0][3] += a[e].x * w[e].w;
            acc[1][0] += a[e].y * w[e].x; acc[1][1] += a[e].y * w[e].y;
            acc[1][2] += a[e].y * w[e].z; acc[1][3] += a[e].y * w[e].w;
            acc[2][0] += a[e].z * w[e].x; acc[2][1] += a[e].z * w[e].y;
            acc[2][2] += a[e].z * w[e].z; acc[2][3] += a[e].z * w[e].w;
            acc[3][0] += a[e].w * w[e].x; acc[3][1] += a[e].w * w[e].y;
            acc[3][2] += a[e].w * w[e].z; acc[3][3] += a[e].w * w[e].w;
        }
    }

    // ---- store 4 rows x float4 ----
    #pragma unroll
    for (int r = 0; r < 4; ++r) {
        const size_t row = row0 + 4 * ti + r;
        float4 v; v.x = acc[r][0]; v.y = acc[r][1]; v.z = acc[r][2]; v.w = acc[r][3];
        *(float4*)(pre + row * GG + gbase + 4 * tj) = v;
    }
}

// =============================================================================
extern "C" void kernel_launch(void* const* d_in, const int* in_sizes, int n_in,
                              void* d_out, int out_size, void* d_ws, size_t ws_size,
                              hipStream_t stream) {
    const float* x         = (const float*)d_in[0];
    const float* W_ih0     = (const float*)d_in[1];
    const float* W_ih_rest = (const float*)d_in[2];
    const float* W_hh      = (const float*)d_in[3];
    const float* b_ih      = (const float*)d_in[4];
    const float* b_hh      = (const float*)d_in[5];
    const float* head_w    = (const float*)d_in[6];
    const float* head_b    = (const float*)d_in[7];
    float* out = (float*)d_out;

    const size_t HS_BYTES = (size_t)BB * TT * HH * 4;   // 52.4 MB
    float* hs  = (float*)d_ws;
    float* pre = (float*)((char*)d_ws + HS_BYTES);      // 209.7 MB

    dim3 ggrid(2048, 5);

    lstm_recur<0><<<256, 512, 0, stream>>>(
        x, nullptr, W_hh, W_ih0, b_ih, b_hh, head_w, head_b, hs, out);

    gemm_pre<<<ggrid, 320, 0, stream>>>(hs, W_ih_rest, b_ih + GG, b_hh + GG, pre);
    lstm_recur<1><<<256, 512, 0, stream>>>(
        nullptr, pre, W_hh + 40000, nullptr, nullptr, nullptr, head_w, head_b, hs, out);

    gemm_pre<<<ggrid, 320, 0, stream>>>(hs, W_ih_rest + 40000, b_ih + 2*GG, b_hh + 2*GG, pre);
    lstm_recur<2><<<256, 512, 0, stream>>>(
        nullptr, pre, W_hh + 80000, nullptr, nullptr, nullptr, head_w, head_b, hs, out);
}

// Round 4
// 1254.763 us; speedup vs baseline: 2.5154x; 1.1899x over previous
//
#include <hip/hip_runtime.h>
#include <math.h>

#define TT 256
#define HH 100
#define GG 400
#define BB 512

// ---- DPP quad-perm helpers (4-lane groups; VALU pipe, NOT ds_swizzle) ------
#define DPP_ROT1 147   // dest l <- src (l-1)&3 : perm [3,0,1,2]
#define DPP_ROT2 78    // dest l <- src (l-2)&3 : perm [2,3,0,1]
#define DPP_ROT3 57    // dest l <- src (l-3)&3 : perm [1,2,3,0]
#define DPP_XOR1 177   // perm [1,0,3,2]
#define DPP_XOR2 78    // perm [2,3,0,1]
#define DPP_XOR3 27    // perm [3,2,1,0]

template<int CTRL>
__device__ __forceinline__ float dppf(float v) {
    int i = __float_as_int(v);
    int r = __builtin_amdgcn_update_dpp(i, i, CTRL, 0xf, 0xf, false);
    return __int_as_float(r);
}

// LDS-drain-only barrier: keeps global loads/stores in flight
__device__ __forceinline__ void bar_lds() {
    asm volatile("s_waitcnt lgkmcnt(0)" ::: "memory");
    __builtin_amdgcn_s_barrier();
    asm volatile("" ::: "memory");
}

// ============================ recurrence kernel ==============================
// 256 blocks x 512 threads, 2 batch rows/block, 1 barrier/step.
// Thread (u = tid>>2, ty = tid&3): computes k-quarter [25*ty, 25*ty+25) partial
// dots for the 4 gates {((ty+d)&3)*100+u, d=0..3} of unit u, both rows.
// Partials combined across the quad with 3 DPP rotations; activations combined
// with 3 DPP xors; ty0 lane updates row0 c/h, ty1 lane updates row1.
// h double-buffered in LDS as [buf][row][quarter][28] (16B-aligned quarters).
template<int LK>
__global__ void __launch_bounds__(512, 1)
lstm_recur(const float* __restrict__ x,        // [B][T][2]   (LK==0)
           const float* __restrict__ pre,      // [T*B][400]  (LK>=1, bias folded)
           const float* __restrict__ Whh,      // [400][100]
           const float* __restrict__ Wih0,     // [400][2]    (LK==0)
           const float* __restrict__ bih,      // [400]       (LK==0)
           const float* __restrict__ bhh,      // [400]       (LK==0)
           const float* __restrict__ head_w,   // [100]
           const float* __restrict__ head_b,   // [1]
           float* __restrict__ hs,             // [B][T][100] (LK<2 out)
           float* __restrict__ out)            // [B]         (LK==2 out)
{
    __shared__ float hbuf[2][2][4][28];   // [buf][row][quarter][25 used + 3 pad]

    const int tid = threadIdx.x;
    const int b0  = blockIdx.x * 2;
    const int u   = tid >> 2, ty = tid & 3;
    const int g   = ty * HH + u;               // own gate row
    const bool on = (tid < GG);

    // Wq[d][k] = Whh[((ty+d)&3)*100 + u][25*ty + k]
    float Wq[4][25];
    float w0a = 0.f, w0b = 0.f, bias = 0.f;
    if (on) {
        #pragma unroll
        for (int d = 0; d < 4; ++d) {
            const int gg = ((ty + d) & 3) * HH + u;
            const float* wp = Whh + gg * HH + 25 * ty;
            #pragma unroll
            for (int k = 0; k < 25; ++k) Wq[d][k] = wp[k];
        }
        if (LK == 0) {
            w0a = Wih0[2 * g]; w0b = Wih0[2 * g + 1];
            bias = bih[g] + bhh[g];
        }
    }
    if (tid < 224) (&hbuf[0][0][0][0])[tid] = 0.f;   // zero buf 0 (incl. pads)
    float c = 0.f;     // ty0: c of row0; ty1: c of row1
    const int q_w = u / 25, i_w = u % 25;            // writer position
    __syncthreads();

    // prefetch t=0 inputs
    float p0 = 0.f, p1 = 0.f;
    float2 xa = {0.f, 0.f}, xb = {0.f, 0.f};
    if (on) {
        if (LK == 0) {
            xa = *(const float2*)(x + (size_t)(b0    ) * TT * 2);
            xb = *(const float2*)(x + (size_t)(b0 + 1) * TT * 2);
        } else {
            p0 = pre[((size_t)0 * BB + b0    ) * GG + g];
            p1 = pre[((size_t)0 * BB + b0 + 1) * GG + g];
        }
    }

    #pragma unroll 2
    for (int t = 0; t < TT; ++t) {
        const int cur = t & 1, nxt = cur ^ 1;
        if (on) {
            // own-gate external input per row
            float ext0, ext1;
            if (LK == 0) {
                ext0 = bias + w0a * xa.x + w0b * xa.y;
                ext1 = bias + w0a * xb.x + w0b * xb.y;
            } else {
                ext0 = p0; ext1 = p1;
            }
            // prefetch t+1 (stays in flight across the raw barrier)
            const int tn = (t + 1 < TT) ? t + 1 : t;
            if (LK == 0) {
                xa = *(const float2*)(x + ((size_t)(b0    ) * TT + tn) * 2);
                xb = *(const float2*)(x + ((size_t)(b0 + 1) * TT + tn) * 2);
            } else {
                p0 = pre[((size_t)tn * BB + b0    ) * GG + g];
                p1 = pre[((size_t)tn * BB + b0 + 1) * GG + g];
            }

            float s0, s1;
            #pragma unroll
            for (int r = 0; r < 2; ++r) {
                const float* hq = &hbuf[cur][r][ty][0];
                float4 H[7];
                #pragma unroll
                for (int i = 0; i < 7; ++i) H[i] = *(const float4*)(hq + 4 * i);

                float pA = 0.f, pB = 0.f, pC = 0.f, pD = 0.f;
                #pragma unroll
                for (int i = 0; i < 6; ++i) {
                    const float4 h4 = H[i];
                    pA += Wq[0][4*i+0] * h4.x; pB += Wq[1][4*i+0] * h4.x;
                    pC += Wq[2][4*i+0] * h4.x; pD += Wq[3][4*i+0] * h4.x;
                    pA += Wq[0][4*i+1] * h4.y; pB += Wq[1][4*i+1] * h4.y;
                    pC += Wq[2][4*i+1] * h4.y; pD += Wq[3][4*i+1] * h4.y;
                    pA += Wq[0][4*i+2] * h4.z; pB += Wq[1][4*i+2] * h4.z;
                    pC += Wq[2][4*i+2] * h4.z; pD += Wq[3][4*i+2] * h4.z;
                    pA += Wq[0][4*i+3] * h4.w; pB += Wq[1][4*i+3] * h4.w;
                    pC += Wq[2][4*i+3] * h4.w; pD += Wq[3][4*i+3] * h4.w;
                }
                const float hl = H[6].x;   // k = 24
                pA += Wq[0][24] * hl; pB += Wq[1][24] * hl;
                pC += Wq[2][24] * hl; pD += Wq[3][24] * hl;

                // cross-quad combine: lane j gets gate-j partials from j-1,j-2,j-3
                float tot = pA + dppf<DPP_ROT1>(pB) + dppf<DPP_ROT2>(pC)
                               + dppf<DPP_ROT3>(pD) + (r == 0 ? ext0 : ext1);

                // activation by own role (ty==2 is the g-gate -> tanh)
                const bool isG = (ty == 2);
                float v = isG ? 2.f * tot : tot;
                float s = 1.f / (1.f + __expf(-v));
                if (isG) s = 2.f * s - 1.f;
                if (r == 0) s0 = s; else s1 = s;
            }

            // gather the other three activated gates (all quad lanes active)
            float B0 = dppf<DPP_XOR1>(s0), C0 = dppf<DPP_XOR2>(s0), D0 = dppf<DPP_XOR3>(s0);
            float B1 = dppf<DPP_XOR1>(s1), C1 = dppf<DPP_XOR2>(s1), D1 = dppf<DPP_XOR3>(s1);

            if (ty == 0) {          // row0: s0=sig(i), B0=sig(f), C0=tanh(g), D0=sig(o)
                c = B0 * c + s0 * C0;
                float th = 2.f / (1.f + __expf(-2.f * c)) - 1.f;
                float hv = D0 * th;
                hbuf[nxt][0][q_w][i_w] = hv;
                if (LK < 2) hs[((size_t)(b0    ) * TT + t) * HH + u] = hv;
            } else if (ty == 1) {   // row1: s1=sig(f), B1=sig(i), C1=sig(o), D1=tanh(g)
                c = s1 * c + B1 * D1;
                float th = 2.f / (1.f + __expf(-2.f * c)) - 1.f;
                float hv = C1 * th;
                hbuf[nxt][1][q_w][i_w] = hv;
                if (LK < 2) hs[((size_t)(b0 + 1) * TT + t) * HH + u] = hv;
            }
        }
        bar_lds();   // h(t) visible; orders hbuf[cur] reuse at t+1
    }

    // head: final h is in hbuf[0] (t=255 wrote nxt=0)
    if (LK == 2) {
        const int lane = tid & 63, wv = tid >> 6;
        if (wv < 2) {
            float p = hbuf[0][wv][lane / 25][lane % 25] * head_w[lane];
            if (lane < 36) {
                const int k2 = 64 + lane;
                p += hbuf[0][wv][k2 / 25][k2 % 25] * head_w[k2];
            }
            #pragma unroll
            for (int off = 32; off; off >>= 1) p += __shfl_down(p, off);
            if (lane == 0) out[b0 + wv] = p + head_b[0];
        }
    }
}

// ============================ x-projection GEMM ==============================
// pre[row][g] = bias[g] + sum_k hs[b][t][k]*Wih[g][k], row = t*512+b.
// M=131072, N=400, K=100. block(320) = 64 rows x 80 gates, frag 4x4.
__global__ void __launch_bounds__(320, 2)
gemm_pre(const float* __restrict__ hs,     // [B][T][100]
         const float* __restrict__ Wih,    // [400][100]
         const float* __restrict__ bih,    // [400]
         const float* __restrict__ bhh,    // [400]
         float* __restrict__ pre)          // [M][400]
{
    __shared__ float A_s[100 * 64];        // k-major, swizzled
    __shared__ float W_s[100 * 80];        // k-major

    const int tid = threadIdx.x;
    const int ti  = tid / 20;              // 0..15 row group
    const int tj  = tid % 20;              // 0..19 gate group
    const int row0   = blockIdx.x * 64;    // 64 rows, same t (512%64==0)
    const int t      = row0 >> 9;
    const int b_base = row0 & 511;
    const int gbase  = blockIdx.y * 80;

    #pragma unroll
    for (int s = 0; s < 5; ++s) {
        const int L  = tid + 320 * s;
        const int r  = L / 25, kq = L % 25;
        float4 v = *(const float4*)(hs + ((size_t)(b_base + r) * TT + t) * HH + 4 * kq);
        const int r4 = r >> 2, rm = r & 3;
        A_s[(4*kq+0)*64 + (((r4) ^ (kq & 15)) << 2) + rm] = v.x;
        A_s[(4*kq+1)*64 + (((r4) ^ (kq & 15)) << 2) + rm] = v.y;
        A_s[(4*kq+2)*64 + (((r4) ^ (kq & 15)) << 2) + rm] = v.z;
        A_s[(4*kq+3)*64 + (((r4) ^ (kq & 15)) << 2) + rm] = v.w;
    }
    for (int L = tid; L < 2000; L += 320) {
        const int kq = L / 80, gl = L % 80;
        float4 v = *(const float4*)(Wih + (size_t)(gbase + gl) * HH + 4 * kq);
        W_s[(4*kq+0)*80 + gl] = v.x;
        W_s[(4*kq+1)*80 + gl] = v.y;
        W_s[(4*kq+2)*80 + gl] = v.z;
        W_s[(4*kq+3)*80 + gl] = v.w;
    }
    __syncthreads();

    float4 bs;
    {
        const float4 b1 = *(const float4*)(bih + gbase + 4 * tj);
        const float4 b2 = *(const float4*)(bhh + gbase + 4 * tj);
        bs.x = b1.x + b2.x; bs.y = b1.y + b2.y; bs.z = b1.z + b2.z; bs.w = b1.w + b2.w;
    }
    float acc[4][4];
    #pragma unroll
    for (int r = 0; r < 4; ++r) {
        acc[r][0] = bs.x; acc[r][1] = bs.y; acc[r][2] = bs.z; acc[r][3] = bs.w;
    }

    #pragma unroll 5
    for (int k4 = 0; k4 < 25; ++k4) {
        const int axo = ((ti ^ (k4 & 15)) << 2);
        float4 a[4], w[4];
        #pragma unroll
        for (int e = 0; e < 4; ++e) {
            a[e] = *(const float4*)&A_s[(4*k4+e)*64 + axo];
            w[e] = *(const float4*)&W_s[(4*k4+e)*80 + (tj << 2)];
        }
        #pragma unroll
        for (int e = 0; e < 4; ++e) {
            acc[0][0] += a[e].x * w[e].x; acc[0][1] += a[e].x * w[e].y;
            acc[0][2] += a[e].x * w[e].z; acc[0][3] += a[e].x * w[e].w;
            acc[1][0] += a[e].y * w[e].x; acc[1][1] += a[e].y * w[e].y;
            acc[1][2] += a[e].y * w[e].z; acc[1][3] += a[e].y * w[e].w;
            acc[2][0] += a[e].z * w[e].x; acc[2][1] += a[e].z * w[e].y;
            acc[2][2] += a[e].z * w[e].z; acc[2][3] += a[e].z * w[e].w;
            acc[3][0] += a[e].w * w[e].x; acc[3][1] += a[e].w * w[e].y;
            acc[3][2] += a[e].w * w[e].z; acc[3][3] += a[e].w * w[e].w;
        }
    }

    #pragma unroll
    for (int r = 0; r < 4; ++r) {
        const size_t row = row0 + 4 * ti + r;
        float4 v; v.x = acc[r][0]; v.y = acc[r][1]; v.z = acc[r][2]; v.w = acc[r][3];
        *(float4*)(pre + row * GG + gbase + 4 * tj) = v;
    }
}

// =============================================================================
extern "C" void kernel_launch(void* const* d_in, const int* in_sizes, int n_in,
                              void* d_out, int out_size, void* d_ws, size_t ws_size,
                              hipStream_t stream) {
    const float* x         = (const float*)d_in[0];
    const float* W_ih0     = (const float*)d_in[1];
    const float* W_ih_rest = (const float*)d_in[2];
    const float* W_hh      = (const float*)d_in[3];
    const float* b_ih      = (const float*)d_in[4];
    const float* b_hh      = (const float*)d_in[5];
    const float* head_w    = (const float*)d_in[6];
    const float* head_b    = (const float*)d_in[7];
    float* out = (float*)d_out;

    const size_t HS_BYTES = (size_t)BB * TT * HH * 4;   // 52.4 MB
    float* hs  = (float*)d_ws;
    float* pre = (float*)((char*)d_ws + HS_BYTES);      // 209.7 MB

    dim3 ggrid(2048, 5);

    lstm_recur<0><<<256, 512, 0, stream>>>(
        x, nullptr, W_hh, W_ih0, b_ih, b_hh, head_w, head_b, hs, out);

    gemm_pre<<<ggrid, 320, 0, stream>>>(hs, W_ih_rest, b_ih + GG, b_hh + GG, pre);
    lstm_recur<1><<<256, 512, 0, stream>>>(
        nullptr, pre, W_hh + 40000, nullptr, nullptr, nullptr, head_w, head_b, hs, out);

    gemm_pre<<<ggrid, 320, 0, stream>>>(hs, W_ih_rest + 40000, b_ih + 2*GG, b_hh + 2*GG, pre);
    lstm_recur<2><<<256, 512, 0, stream>>>(
        nullptr, pre, W_hh + 80000, nullptr, nullptr, nullptr, head_w, head_b, hs, out);
}